// Round 9
// baseline (164.014 us; speedup 1.0000x reference)
//
#include <hip/hip_runtime.h>
#include <stdint.h>

// Problem constants (fixed by the reference)
#define BATCH   4096
#define IN_DIM  1024
#define OUT_DIM 1024

typedef __bf16 bf16x8 __attribute__((ext_vector_type(8)));
typedef float  f32x4  __attribute__((ext_vector_type(4)));

// fp32 -> bf16 bits, round-to-nearest-even
__device__ __forceinline__ uint16_t f2bf(float f) {
    union { float f; uint32_t u; } v; v.f = f;
    uint32_t u = v.u;
    uint32_t r = (u + 0x7FFFu + ((u >> 16) & 1u)) >> 16;
    return (uint16_t)r;
}

__device__ __forceinline__ float bf2f(uint16_t h) {
    union { uint32_t u; float f; } v; v.u = ((uint32_t)h) << 16;
    return v.f;
}

// ---------------------------------------------------------------------------
// prep: blocks 0..4095   -> convert x row b to bf16, compute alpha[b][0..3]
//       blocks 4096..8191 -> convert W (flat 4M floats) to bf16
// ---------------------------------------------------------------------------
__global__ __launch_bounds__(256) void prep(
    const float* __restrict__ x, const float* __restrict__ phase,
    const float* __restrict__ basis, const float* __restrict__ W,
    uint16_t* __restrict__ xb, uint16_t* __restrict__ Wb,
    float* __restrict__ alphaWS)
{
    const int bid = blockIdx.x;
    const int tid = threadIdx.x;

    if (bid < BATCH) {
        const int b = bid;
        const float HALF_PI = 1.5707963267948966f;
        float s  = phase[b] / HALF_PI;
        int   q  = (int)floorf(s);
        q = q < 0 ? 0 : (q > 3 ? 3 : q);
        float t  = s - (float)q;
        float t2 = t * t, t3 = t2 * t;

        float coef[4];
#pragma unroll
        for (int j = 0; j < 4; ++j)
            coef[j] = t3 * basis[j] + t2 * basis[4 + j] + t * basis[8 + j] + basis[12 + j];

        // CPI[q][k] = (q+k+3)%4  =>  alpha[c] = coef[(c - q + 1) & 3]
        if (tid < 4) alphaWS[b * 4 + tid] = coef[(tid - q + 1) & 3];

        float4 xv = ((const float4*)(x + (size_t)b * IN_DIM))[tid];
        ushort4 o;
        o.x = f2bf(xv.x); o.y = f2bf(xv.y); o.z = f2bf(xv.z); o.w = f2bf(xv.w);
        ((ushort4*)(xb + (size_t)b * IN_DIM))[tid] = o;
    } else {
        const int j = bid - BATCH;                 // 0..4095, W has 1M float4s
        float4 wv = ((const float4*)W)[j * 256 + tid];
        ushort4 o;
        o.x = f2bf(wv.x); o.y = f2bf(wv.y); o.z = f2bf(wv.z); o.w = f2bf(wv.w);
        ((ushort4*)Wb)[j * 256 + tid] = o;
    }
}

// ---------------------------------------------------------------------------
// gemm_fused: ROUND-6 skeleton (best) with B moved OUT of LDS.
// One block = one 64x64 out-tile; wave wid = control point c.
//  - B_c is wave-PRIVATE (zero intra-block sharing) and its MFMA fragment is
//    lane-contiguous in Wb's [n][k] layout -> load fragments DIRECTLY from
//    global into registers (16B aligned, 64B coalesced per quad group,
//    L1/L2-served). Deletes 8 gload_lds + 8 ds_read per K-step and removes
//    B from the barrier-drain path entirely.
//  - A (shared by the 4 waves) keeps the verified gload_lds XOR staging,
//    2 slices/wave, 2 barriers per K-step (round-0/6 proven math).
//  - LDS = max(As 8KB, epilogue Ps 33.8KB) = 33792 B -> 4 blocks/CU
//    (round 8's 80KB dbuf gave 2 blocks/CU and was null: latency hiding on
//    this chip comes from cross-block TLP, not intra-wave ILP [m114/m97]).
//  - XCD-chunked bijective swizzle (1024 blocks = 8 XCDs x 128): XCD j owns
//    by in {2j,2j+1} -> its 8 B panels (1MB) stay L2-resident.
// Epilogue: round-6 verified in-block c-reduction via Ps LDS exchange.
// ---------------------------------------------------------------------------
#define PS 66   // padded row stride (elems) for epilogue exchange

__global__ __launch_bounds__(256, 4) void gemm_fused(
    const uint16_t* __restrict__ xb, const uint16_t* __restrict__ Wb,
    const float* __restrict__ alphaWS, const float* __restrict__ biases,
    float* __restrict__ out)
{
    __shared__ uint16_t lds[4 * 64 * PS];   // 33792 B
    uint16_t* As = lds;                     // [64][64] A staging (8KB, aliased)
    uint16_t* Ps = lds;                     // epilogue [4][64][PS]

    const int tid  = threadIdx.x;
    const int lane = tid & 63;
    const int wid  = tid >> 6;        // = c for this wave

    // XCD-chunked swizzle: hw dispatches linear id round-robin over 8 XCDs;
    // remap so XCD j gets a contiguous 128-block chunk (by in {2j, 2j+1}).
    const int lid = blockIdx.x + (blockIdx.y << 6);
    const int nid = (lid & 7) * 128 + (lid >> 3);      // bijective (1024%8==0)
    const int tileM = (nid & 63) * 64;
    const int tileN = (nid >> 6) * 64;

    f32x4 acc[4][4];
#pragma unroll
    for (int mi = 0; mi < 4; ++mi)
#pragma unroll
        for (int ni = 0; ni < 4; ++ni)
            acc[mi][ni] = (f32x4){0.f, 0.f, 0.f, 0.f};

    // A staging: slice = 8 rows x 64 cols; lane l -> row l>>3, phys chunk l&7,
    // source global chunk = (l&7) ^ (l>>3)   (XOR swizzle, round-0 verified)
    const int srow = lane >> 3;
    const int gchunk = ((lane & 7) ^ srow) * 8;

    const uint16_t* Ag = xb + (size_t)tileM * 1024;
    const uint16_t* Bg = Wb + ((size_t)wid << 20) + (size_t)tileN * 1024;

    const int quad = lane >> 4;
    const int l7   = lane & 7;

    // B fragment base offsets for this lane: row (lane&15), k-chunk quad
    const int bn = (lane & 15) * 1024;    // row offset (elems)
    const int bk = quad * 8;              // k offset within 64-elem chunk group

    for (int kt = 0; kt < 16; ++kt) {
        const int k0 = kt * 64;

        __syncthreads();                  // previous K-step's As reads done

        // A: 8 slices total, wave stages 2 (shared by all 4 waves)
#pragma unroll
        for (int j = 0; j < 2; ++j) {
            const int s = wid * 2 + j;
            const uint16_t* ga = Ag + (size_t)(s * 8 + srow) * 1024 + k0 + gchunk;
            __builtin_amdgcn_global_load_lds(
                (const __attribute__((address_space(1))) void*)ga,
                (__attribute__((address_space(3))) void*)(As + s * 512), 16, 0, 0);
        }

        // B fragments direct from global (bit-identical values to the old
        // LDS path): Wb[c][tileN+ni*16+(lane&15)][k0+(ks*4+quad)*8 .. +8]
        bf16x8 b0[4], b1[4];
#pragma unroll
        for (int ni = 0; ni < 4; ++ni) {
            b0[ni] = *(const bf16x8*)(Bg + ni * 16384 + bn + k0 + bk);        // ks=0
            b1[ni] = *(const bf16x8*)(Bg + ni * 16384 + bn + k0 + 32 + bk);   // ks=1
        }

        __syncthreads();                  // As ready (compiler drains vmcnt)

#pragma unroll
        for (int ks = 0; ks < 2; ++ks) {
            const int ch = (ks * 4 + quad) ^ l7;       // physical chunk (A)
            bf16x8 af[4];
#pragma unroll
            for (int mi = 0; mi < 4; ++mi) {
                const int row = mi * 16 + (lane & 15);
                af[mi] = *(const bf16x8*)(As + row * 64 + ch * 8);
            }
#pragma unroll
            for (int mi = 0; mi < 4; ++mi)
#pragma unroll
                for (int ni = 0; ni < 4; ++ni)
                    acc[mi][ni] = __builtin_amdgcn_mfma_f32_16x16x32_bf16(
                        af[mi], ks ? b1[ni] : b0[ni], acc[mi][ni], 0, 0, 0);
        }
    }

    // ---- epilogue: in-block c-reduction (round-6 verified) ----
    // 1) scale by alpha[m, c=wid], publish bf16 partials to Ps.
    //    C/D layout: col = lane&15, row(64-tile) = mi*16 + quad*4 + r.
    float av[4][4];
#pragma unroll
    for (int mi = 0; mi < 4; ++mi)
#pragma unroll
        for (int r = 0; r < 4; ++r)
            av[mi][r] = alphaWS[(size_t)(tileM + mi * 16 + quad * 4 + r) * 4 + wid];

    __syncthreads();                      // last K-step's As reads complete
#pragma unroll
    for (int mi = 0; mi < 4; ++mi) {
#pragma unroll
        for (int r = 0; r < 4; ++r) {
            const int row = mi * 16 + quad * 4 + r;
#pragma unroll
            for (int ni = 0; ni < 4; ++ni)
                Ps[wid * (64 * PS) + row * PS + ni * 16 + (lane & 15)] =
                    f2bf(av[mi][r] * acc[mi][ni][r]);
        }
    }
    __syncthreads();

    // 2) combine: thread t -> row rr = t>>2, 16-col group cg = t&3.
    //    out[m,n] = sum_c Ps_c[m,n] + sum_c alpha[m,c]*bias[c,n]
    {
        const int rr = tid >> 2;
        const int cg = tid & 3;
        const int colb = cg * 16;
        const float4 al = *(const float4*)(alphaWS + (size_t)(tileM + rr) * 4);
        const float a[4] = {al.x, al.y, al.z, al.w};

        float res[16];
#pragma unroll
        for (int j = 0; j < 16; ++j) res[j] = 0.f;

#pragma unroll
        for (int cc = 0; cc < 4; ++cc) {
            // alpha-weighted bias (bias is L2-hot, 16KB total)
#pragma unroll
            for (int jj = 0; jj < 4; ++jj) {
                float4 bv = *(const float4*)(biases + (size_t)cc * OUT_DIM + tileN + colb + jj * 4);
                res[jj * 4 + 0] += a[cc] * bv.x;
                res[jj * 4 + 1] += a[cc] * bv.y;
                res[jj * 4 + 2] += a[cc] * bv.z;
                res[jj * 4 + 3] += a[cc] * bv.w;
            }
            // partial (ushort2 = 4B aligned: offsets all even)
            const uint16_t* p = Ps + cc * (64 * PS) + rr * PS + colb;
#pragma unroll
            for (int jj = 0; jj < 8; ++jj) {
                uint32_t pv = *(const uint32_t*)(p + jj * 2);
                res[jj * 2 + 0] += bf2f((uint16_t)(pv & 0xFFFFu));
                res[jj * 2 + 1] += bf2f((uint16_t)(pv >> 16));
            }
        }

        float* orow = out + (size_t)(tileM + rr) * OUT_DIM + tileN + colb;
#pragma unroll
        for (int jj = 0; jj < 4; ++jj) {
            float4 o = {res[jj * 4 + 0], res[jj * 4 + 1], res[jj * 4 + 2], res[jj * 4 + 3]};
            *(float4*)(orow + jj * 4) = o;
        }
    }
}

extern "C" void kernel_launch(void* const* d_in, const int* in_sizes, int n_in,
                              void* d_out, int out_size, void* d_ws, size_t ws_size,
                              hipStream_t stream)
{
    const float* x       = (const float*)d_in[0];  // (B, IN)
    const float* phase   = (const float*)d_in[1];  // (B,)
    const float* weights = (const float*)d_in[2];  // (4, OUT, IN)
    const float* biases  = (const float*)d_in[3];  // (4, OUT)
    const float* basis   = (const float*)d_in[4];  // (4, 4)
    float* out = (float*)d_out;                    // (B, OUT)

    // Workspace: xb bf16 8 MB | Wb bf16 8 MB | alpha 64 KB
    uint16_t* xb = (uint16_t*)d_ws;
    uint16_t* Wb = xb + (size_t)BATCH * IN_DIM;
    float* alphaWS = (float*)(Wb + (size_t)4 * OUT_DIM * IN_DIM);

    prep<<<2 * BATCH, 256, 0, stream>>>(x, phase, basis, weights, xb, Wb, alphaWS);

    dim3 grid(BATCH / 64, OUT_DIM / 64);   // 1024 blocks (remapped in-kernel)
    gemm_fused<<<grid, 256, 0, stream>>>(xb, Wb, alphaWS, biases, out);
}

// Round 10
// 152.678 us; speedup vs baseline: 1.0742x; 1.0742x over previous
//
#include <hip/hip_runtime.h>
#include <stdint.h>

// Problem constants (fixed by the reference)
#define BATCH   4096
#define IN_DIM  1024
#define OUT_DIM 1024

typedef __bf16 bf16x8 __attribute__((ext_vector_type(8)));
typedef float  f32x4  __attribute__((ext_vector_type(4)));

__device__ __forceinline__ float bf2f(uint16_t h) {
    union { uint32_t u; float f; } v; v.u = ((uint32_t)h) << 16;
    return v.f;
}

// ---------------------------------------------------------------------------
// fused: ONE kernel, no prep, no workspace.
// R6 skeleton (best gemm: 46.6 us): one block = one 64x64 out-tile; wave
// wid = control point c; A shared [64][64], B_c private [64][64] in LDS;
// in-block c-reduction epilogue (cross-block coherence refuted R2-R5).
//
// Change vs R6/R8: staging converts f32->bf16 INLINE. Each wave loads its
// slice rows as f32 (coalesced 256B/row: lanes 0-7 cover one row's 8
// swizzled chunks), converts via native (__bf16) casts (RNE, bit-identical
// to the old prep's round-to-nearest-even), and ds_write_b128's to the SAME
// physical layout global_load_lds produced (dest = slice*512 + lane*8
// elems). Read side byte-identical to R0/R6: phys chunk=(ks*4+quad)^(lane&7).
// This deletes the prep kernel (~10us), one launch gap (~9us), and 16MB of
// xb/Wb writes. alpha is computed in-epilogue from phase into a 1KB LDS
// table (placed in Bs's tail, dead after the K-loop); bias read f32 direct.
// XCD-chunked bijective swizzle keeps each XCD's W f32 working set (2MB)
// L2-resident. LDS 40KB -> 4 blocks/CU (TLP does the latency hiding; R8
// proved dbuf-at-2-blocks is null).
// ---------------------------------------------------------------------------
#define PS 66   // padded row stride (elems) for epilogue exchange

__global__ __launch_bounds__(256, 4) void fused(
    const float* __restrict__ x, const float* __restrict__ phase,
    const float* __restrict__ basis, const float* __restrict__ W,
    const float* __restrict__ biases, float* __restrict__ out)
{
    __shared__ uint16_t lds[20480];           // 40 KB
    uint16_t* As = lds;                       // [64][64] A staging (8 KB)
    uint16_t* Bs = lds + 4096;                // [4][64][64] B staging (32 KB)
    uint16_t* Ps = lds;                       // epilogue alias [4][64][PS] (33.8 KB)
    float* alphaS = (float*)(lds + 18432);    // [64][4] f32 (1 KB, Bs tail — dead post-K)

    const int tid  = threadIdx.x;
    const int lane = tid & 63;
    const int wid  = tid >> 6;        // = c for this wave

    // XCD-chunked bijective swizzle (1024 blocks = 8 XCDs x 128)
    const int lid = blockIdx.x + (blockIdx.y << 6);
    const int nid = (lid & 7) * 128 + (lid >> 3);
    const int tileM = (nid & 63) * 64;
    const int tileN = (nid >> 6) * 64;

    f32x4 acc[4][4];
#pragma unroll
    for (int mi = 0; mi < 4; ++mi)
#pragma unroll
        for (int ni = 0; ni < 4; ++ni)
            acc[mi][ni] = (f32x4){0.f, 0.f, 0.f, 0.f};

    // staging geometry (round-0 verified): slice = 8 rows x 64 cols;
    // lane l -> row l>>3, phys chunk l&7, source chunk (l&7)^(l>>3)
    const int srow   = lane >> 3;
    const int gchunk = ((lane & 7) ^ srow) * 8;   // element offset (same in f32)
    const int dst8   = lane * 8;                  // dest elem offset in slice

    const float* Ag = x + (size_t)tileM * 1024;
    const float* Bg = W + ((size_t)wid << 20) + (size_t)tileN * 1024;

    const int quad = lane >> 4;
    const int l7   = lane & 7;

    for (int kt = 0; kt < 16; ++kt) {
        const int k0 = kt * 64;

        __syncthreads();              // previous K-step's LDS reads done

        // stage A: 2 slices/wave (shared by all 4 waves), f32 -> bf16 inline
#pragma unroll
        for (int j = 0; j < 2; ++j) {
            const int s = wid * 2 + j;
            const float* ga = Ag + (size_t)(s * 8 + srow) * 1024 + k0 + gchunk;
            float4 v0 = *(const float4*)ga;
            float4 v1 = *(const float4*)(ga + 4);
            bf16x8 o;
            o[0] = (__bf16)v0.x; o[1] = (__bf16)v0.y;
            o[2] = (__bf16)v0.z; o[3] = (__bf16)v0.w;
            o[4] = (__bf16)v1.x; o[5] = (__bf16)v1.y;
            o[6] = (__bf16)v1.z; o[7] = (__bf16)v1.w;
            *(bf16x8*)(As + s * 512 + dst8) = o;
        }
        // stage B_c: 8 slices, this wave's own control point
#pragma unroll
        for (int j = 0; j < 8; ++j) {
            const float* gb = Bg + (size_t)(j * 8 + srow) * 1024 + k0 + gchunk;
            float4 v0 = *(const float4*)gb;
            float4 v1 = *(const float4*)(gb + 4);
            bf16x8 o;
            o[0] = (__bf16)v0.x; o[1] = (__bf16)v0.y;
            o[2] = (__bf16)v0.z; o[3] = (__bf16)v0.w;
            o[4] = (__bf16)v1.x; o[5] = (__bf16)v1.y;
            o[6] = (__bf16)v1.z; o[7] = (__bf16)v1.w;
            *(bf16x8*)(Bs + wid * 4096 + j * 512 + dst8) = o;
        }

        __syncthreads();              // staging visible to all waves

        // compute: byte-identical to R0/R6 verified fragment math
#pragma unroll
        for (int ks = 0; ks < 2; ++ks) {
            const int ch = (ks * 4 + quad) ^ l7;       // physical chunk
            bf16x8 af[4], bfr[4];
#pragma unroll
            for (int mi = 0; mi < 4; ++mi) {
                const int row = mi * 16 + (lane & 15);
                af[mi] = *(const bf16x8*)(As + row * 64 + ch * 8);
            }
#pragma unroll
            for (int ni = 0; ni < 4; ++ni) {
                const int row = ni * 16 + (lane & 15);
                bfr[ni] = *(const bf16x8*)(Bs + wid * 4096 + row * 64 + ch * 8);
            }
#pragma unroll
            for (int mi = 0; mi < 4; ++mi)
#pragma unroll
                for (int ni = 0; ni < 4; ++ni)
                    acc[mi][ni] = __builtin_amdgcn_mfma_f32_16x16x32_bf16(
                        af[mi], bfr[ni], acc[mi][ni], 0, 0, 0);
        }
    }

    __syncthreads();                  // last K-step's LDS reads complete

    // ---- alpha table: thread t -> row t>>2, c t&3 (same formula as prep) ----
    {
        const int r = tid >> 2, c = tid & 3;
        const float HALF_PI = 1.5707963267948966f;
        float s  = phase[tileM + r] / HALF_PI;
        int   q  = (int)floorf(s);
        q = q < 0 ? 0 : (q > 3 ? 3 : q);
        float t  = s - (float)q;
        float t2 = t * t, t3 = t2 * t;
        const int j = (c - q + 1) & 3;    // CPI[q][k]=(q+k+3)%4 inversion
        alphaS[r * 4 + c] = t3 * basis[j] + t2 * basis[4 + j]
                          + t * basis[8 + j] + basis[12 + j];
    }
    __syncthreads();

    // ---- epilogue: in-block c-reduction (R6 verified) ----
    // 1) scale by alpha[m, c=wid], publish bf16 partials to Ps.
    //    C/D layout: col = lane&15, row(64-tile) = mi*16 + quad*4 + r.
    float av[4][4];
#pragma unroll
    for (int mi = 0; mi < 4; ++mi)
#pragma unroll
        for (int r = 0; r < 4; ++r)
            av[mi][r] = alphaS[(mi * 16 + quad * 4 + r) * 4 + wid];

#pragma unroll
    for (int mi = 0; mi < 4; ++mi) {
#pragma unroll
        for (int r = 0; r < 4; ++r) {
            const int row = mi * 16 + quad * 4 + r;
#pragma unroll
            for (int ni = 0; ni < 4; ++ni) {
                __bf16 pb = (__bf16)(av[mi][r] * acc[mi][ni][r]);
                Ps[wid * (64 * PS) + row * PS + ni * 16 + (lane & 15)] =
                    *(uint16_t*)&pb;
            }
        }
    }
    __syncthreads();

    // 2) combine: thread t -> row rr = t>>2, 16-col group cg = t&3.
    //    out[m,n] = sum_c Ps_c[m,n] + sum_c alpha[m,c]*bias[c,n]
    {
        const int rr = tid >> 2;
        const int cg = tid & 3;
        const int colb = cg * 16;
        const float4 al = *(const float4*)(alphaS + rr * 4);
        const float a[4] = {al.x, al.y, al.z, al.w};

        float res[16];
#pragma unroll
        for (int j = 0; j < 16; ++j) res[j] = 0.f;

#pragma unroll
        for (int cc = 0; cc < 4; ++cc) {
            // alpha-weighted bias (16 KB total, L2-hot)
#pragma unroll
            for (int jj = 0; jj < 4; ++jj) {
                float4 bv = *(const float4*)(biases + (size_t)cc * OUT_DIM + tileN + colb + jj * 4);
                res[jj * 4 + 0] += a[cc] * bv.x;
                res[jj * 4 + 1] += a[cc] * bv.y;
                res[jj * 4 + 2] += a[cc] * bv.z;
                res[jj * 4 + 3] += a[cc] * bv.w;
            }
            // partial (ushort2 = 4B aligned: offsets all even)
            const uint16_t* p = Ps + cc * (64 * PS) + rr * PS + colb;
#pragma unroll
            for (int jj = 0; jj < 8; ++jj) {
                uint32_t pv = *(const uint32_t*)(p + jj * 2);
                res[jj * 2 + 0] += bf2f((uint16_t)(pv & 0xFFFFu));
                res[jj * 2 + 1] += bf2f((uint16_t)(pv >> 16));
            }
        }

        float* orow = out + (size_t)(tileM + rr) * OUT_DIM + tileN + colb;
#pragma unroll
        for (int jj = 0; jj < 4; ++jj) {
            float4 o = {res[jj * 4 + 0], res[jj * 4 + 1], res[jj * 4 + 2], res[jj * 4 + 3]};
            *(float4*)(orow + jj * 4) = o;
        }
    }
}

extern "C" void kernel_launch(void* const* d_in, const int* in_sizes, int n_in,
                              void* d_out, int out_size, void* d_ws, size_t ws_size,
                              hipStream_t stream)
{
    const float* x       = (const float*)d_in[0];  // (B, IN)
    const float* phase   = (const float*)d_in[1];  // (B,)
    const float* weights = (const float*)d_in[2];  // (4, OUT, IN)
    const float* biases  = (const float*)d_in[3];  // (4, OUT)
    const float* basis   = (const float*)d_in[4];  // (4, 4)
    float* out = (float*)d_out;                    // (B, OUT)

    dim3 grid(BATCH / 64, OUT_DIM / 64);   // 1024 blocks (remapped in-kernel)
    fused<<<grid, 256, 0, stream>>>(x, phase, basis, weights, biases, out);
}

// Round 11
// 127.382 us; speedup vs baseline: 1.2876x; 1.1986x over previous
//
#include <hip/hip_runtime.h>
#include <stdint.h>

// Problem constants (fixed by the reference)
#define BATCH   4096
#define IN_DIM  1024
#define OUT_DIM 1024

typedef __bf16 bf16x8 __attribute__((ext_vector_type(8)));
typedef float  f32x4  __attribute__((ext_vector_type(4)));

// fp32 -> bf16 bits, round-to-nearest-even
__device__ __forceinline__ uint16_t f2bf(float f) {
    union { float f; uint32_t u; } v; v.f = f;
    uint32_t u = v.u;
    uint32_t r = (u + 0x7FFFu + ((u >> 16) & 1u)) >> 16;
    return (uint16_t)r;
}

__device__ __forceinline__ float bf2f(uint16_t h) {
    union { uint32_t u; float f; } v; v.u = ((uint32_t)h) << 16;
    return v.f;
}

__device__ __forceinline__ ushort4 cvt4(float4 v) {
    ushort4 o;
    o.x = f2bf(v.x); o.y = f2bf(v.y); o.z = f2bf(v.z); o.w = f2bf(v.w);
    return o;
}

// ---------------------------------------------------------------------------
// prep: 2048 blocks (was 8192 — R6's 40us prep+gap residual is dispatch/tail
// dominated, not BW: only 48MB of traffic). Each block does 4x the work:
//   blocks 0..1023    -> x rows 4b..4b+3 -> bf16, plus alpha for those rows
//   blocks 1024..2047 -> 4096 consecutive float4s of W -> bf16
// Same math as R0-verified prep (f2bf RNE), just re-gridded.
// ---------------------------------------------------------------------------
__global__ __launch_bounds__(256) void prep(
    const float* __restrict__ x, const float* __restrict__ phase,
    const float* __restrict__ basis, const float* __restrict__ W,
    uint16_t* __restrict__ xb, uint16_t* __restrict__ Wb,
    float* __restrict__ alphaWS)
{
    const int bid = blockIdx.x;
    const int tid = threadIdx.x;

    if (bid < 1024) {
        const int r0 = bid * 4;
        if (tid < 16) {
            const int r = r0 + (tid >> 2), c = tid & 3;
            const float HALF_PI = 1.5707963267948966f;
            float s  = phase[r] / HALF_PI;
            int   q  = (int)floorf(s);
            q = q < 0 ? 0 : (q > 3 ? 3 : q);
            float t  = s - (float)q;
            float t2 = t * t, t3 = t2 * t;
            // CPI[q][k] = (q+k+3)%4  =>  alpha[c] = coef[(c - q + 1) & 3]
            const int j = (c - q + 1) & 3;
            alphaWS[r * 4 + c] = t3 * basis[j] + t2 * basis[4 + j]
                               + t * basis[8 + j] + basis[12 + j];
        }
        const float4* xs = (const float4*)(x + (size_t)r0 * IN_DIM);
        ushort4*      xd = (ushort4*)(xb + (size_t)r0 * IN_DIM);
#pragma unroll
        for (int j = 0; j < 4; ++j)
            xd[j * 256 + tid] = cvt4(xs[j * 256 + tid]);
    } else {
        const size_t j0 = (size_t)(bid - 1024) * 1024;   // of 1M float4s
        const float4* ws = (const float4*)W;
        ushort4*      wd = (ushort4*)Wb;
#pragma unroll
        for (int j = 0; j < 4; ++j)
            wd[j0 + j * 256 + tid] = cvt4(ws[j0 + j * 256 + tid]);
    }
}

// ---------------------------------------------------------------------------
// gemm_fused: ROUND-6 kernel VERBATIM (best measured: 46.6 us, 737 TF).
// One block = one 64x64 out-tile; wave wid computes control point c = wid
// over the SAME tile (A shared 64x64, B_c private 64x64 in LDS). In-block
// c-reduction epilogue via LDS exchange. Survived A/B vs: dbuf-80KB (R8,
// worse), 8-wave 128x64 (R7, much worse), B-direct-from-global (R9, much
// worse), inline f32 staging (R10, much worse). Cross-block coherence
// mechanisms all refuted (R2-R5). Single-buffer + 4 blocks/CU TLP is the
// proven latency-hiding regime for this shape.
// ---------------------------------------------------------------------------
#define PS 66   // padded row stride (elems) for epilogue exchange

__global__ __launch_bounds__(256, 3) void gemm_fused(
    const uint16_t* __restrict__ xb, const uint16_t* __restrict__ Wb,
    const float* __restrict__ alphaWS, const float* __restrict__ biases,
    float* __restrict__ out)
{
    __shared__ uint16_t lds[64 * 64 + 4 * 64 * 64];   // As 8KB | Bs 32KB (40KB)
    uint16_t* As = lds;                                // [64][64]
    uint16_t* Bs = lds + 4096;                         // [4][64][64]
    uint16_t* Ps = lds;                                // epilogue alias [4][64][PS]

    const int tid  = threadIdx.x;
    const int lane = tid & 63;
    const int wid  = tid >> 6;        // = c for this wave
    const int tileM = blockIdx.x * 64;
    const int tileN = blockIdx.y * 64;

    f32x4 acc[4][4];
#pragma unroll
    for (int mi = 0; mi < 4; ++mi)
#pragma unroll
        for (int ni = 0; ni < 4; ++ni)
            acc[mi][ni] = (f32x4){0.f, 0.f, 0.f, 0.f};

    // staging: slice = 8 rows x 64 cols; lane l -> row l>>3, phys chunk l&7,
    // source global chunk = (l&7) ^ (l>>3)   (XOR swizzle, round-0 verified)
    const int srow = lane >> 3;
    const int gchunk = ((lane & 7) ^ srow) * 8;

    const uint16_t* Ag = xb + (size_t)tileM * 1024;
    const uint16_t* Bg = Wb + ((size_t)wid << 20) + (size_t)tileN * 1024;

    const int quad = lane >> 4;
    const int l7   = lane & 7;

    for (int kt = 0; kt < 16; ++kt) {
        const int k0 = kt * 64;
        // A: 8 slices total, wave stages 2 (shared by all 4 waves)
#pragma unroll
        for (int j = 0; j < 2; ++j) {
            const int s = wid * 2 + j;
            const uint16_t* ga = Ag + (size_t)(s * 8 + srow) * 1024 + k0 + gchunk;
            __builtin_amdgcn_global_load_lds(
                (const __attribute__((address_space(1))) void*)ga,
                (__attribute__((address_space(3))) void*)(As + s * 512), 16, 0, 0);
        }
        // B_c: 8 slices, this wave's own control point
#pragma unroll
        for (int j = 0; j < 8; ++j) {
            const uint16_t* gb = Bg + (size_t)(j * 8 + srow) * 1024 + k0 + gchunk;
            __builtin_amdgcn_global_load_lds(
                (const __attribute__((address_space(1))) void*)gb,
                (__attribute__((address_space(3))) void*)(Bs + wid * 4096 + j * 512), 16, 0, 0);
        }
        __syncthreads();

#pragma unroll
        for (int ks = 0; ks < 2; ++ks) {
            const int ch = (ks * 4 + quad) ^ l7;       // physical chunk
            bf16x8 af[4], bfr[4];
#pragma unroll
            for (int mi = 0; mi < 4; ++mi) {
                const int row = mi * 16 + (lane & 15);
                af[mi] = *(const bf16x8*)(As + row * 64 + ch * 8);
            }
#pragma unroll
            for (int ni = 0; ni < 4; ++ni) {
                const int row = ni * 16 + (lane & 15);
                bfr[ni] = *(const bf16x8*)(Bs + wid * 4096 + row * 64 + ch * 8);
            }
#pragma unroll
            for (int mi = 0; mi < 4; ++mi)
#pragma unroll
                for (int ni = 0; ni < 4; ++ni)
                    acc[mi][ni] = __builtin_amdgcn_mfma_f32_16x16x32_bf16(
                        af[mi], bfr[ni], acc[mi][ni], 0, 0, 0);
        }
        __syncthreads();
    }

    // ---- epilogue: in-block c-reduction ----
    // 1) scale by alpha[m, c=wid] and publish bf16 partials to Ps.
    //    C/D layout: col = lane&15, row(64-tile) = mi*16 + quad*4 + r.
    float av[4][4];
#pragma unroll
    for (int mi = 0; mi < 4; ++mi)
#pragma unroll
        for (int r = 0; r < 4; ++r)
            av[mi][r] = alphaWS[(size_t)(tileM + mi * 16 + quad * 4 + r) * 4 + wid];

#pragma unroll
    for (int mi = 0; mi < 4; ++mi) {
#pragma unroll
        for (int r = 0; r < 4; ++r) {
            const int row = mi * 16 + quad * 4 + r;
#pragma unroll
            for (int ni = 0; ni < 4; ++ni)
                Ps[wid * (64 * PS) + row * PS + ni * 16 + (lane & 15)] =
                    f2bf(av[mi][r] * acc[mi][ni][r]);
        }
    }
    __syncthreads();

    // 2) combine: thread t -> row rr = t>>2, 16-col group cg = t&3.
    //    out[m,n] = sum_c Ps_c[m,n] + sum_c alpha[m,c]*bias[c,n]
    {
        const int rr = tid >> 2;
        const int cg = tid & 3;
        const int colb = cg * 16;
        const float4 al = *(const float4*)(alphaWS + (size_t)(tileM + rr) * 4);
        const float a[4] = {al.x, al.y, al.z, al.w};

        float res[16];
#pragma unroll
        for (int j = 0; j < 16; ++j) res[j] = 0.f;

#pragma unroll
        for (int cc = 0; cc < 4; ++cc) {
            // alpha-weighted bias (bias is L2-hot, 16KB total)
#pragma unroll
            for (int jj = 0; jj < 4; ++jj) {
                float4 bv = *(const float4*)(biases + (size_t)cc * OUT_DIM + tileN + colb + jj * 4);
                res[jj * 4 + 0] += a[cc] * bv.x;
                res[jj * 4 + 1] += a[cc] * bv.y;
                res[jj * 4 + 2] += a[cc] * bv.z;
                res[jj * 4 + 3] += a[cc] * bv.w;
            }
            // partial (ushort2 = 4B aligned: offsets all even)
            const uint16_t* p = Ps + cc * (64 * PS) + rr * PS + colb;
#pragma unroll
            for (int jj = 0; jj < 8; ++jj) {
                uint32_t pv = *(const uint32_t*)(p + jj * 2);
                res[jj * 2 + 0] += bf2f((uint16_t)(pv & 0xFFFFu));
                res[jj * 2 + 1] += bf2f((uint16_t)(pv >> 16));
            }
        }

        float* orow = out + (size_t)(tileM + rr) * OUT_DIM + tileN + colb;
#pragma unroll
        for (int jj = 0; jj < 4; ++jj) {
            float4 o = {res[jj * 4 + 0], res[jj * 4 + 1], res[jj * 4 + 2], res[jj * 4 + 3]};
            *(float4*)(orow + jj * 4) = o;
        }
    }
}

extern "C" void kernel_launch(void* const* d_in, const int* in_sizes, int n_in,
                              void* d_out, int out_size, void* d_ws, size_t ws_size,
                              hipStream_t stream)
{
    const float* x       = (const float*)d_in[0];  // (B, IN)
    const float* phase   = (const float*)d_in[1];  // (B,)
    const float* weights = (const float*)d_in[2];  // (4, OUT, IN)
    const float* biases  = (const float*)d_in[3];  // (4, OUT)
    const float* basis   = (const float*)d_in[4];  // (4, 4)
    float* out = (float*)d_out;                    // (B, OUT)

    // Workspace: xb bf16 8 MB | Wb bf16 8 MB | alpha 64 KB
    uint16_t* xb = (uint16_t*)d_ws;
    uint16_t* Wb = xb + (size_t)BATCH * IN_DIM;
    float* alphaWS = (float*)(Wb + (size_t)4 * OUT_DIM * IN_DIM);

    prep<<<2048, 256, 0, stream>>>(x, phase, basis, weights, xb, Wb, alphaWS);

    dim3 grid(BATCH / 64, OUT_DIM / 64);   // 1024 blocks, M-fastest for L2
    gemm_fused<<<grid, 256, 0, stream>>>(xb, Wb, alphaWS, biases, out);
}